// Round 1
// baseline (16083.311 us; speedup 1.0000x reference)
//
#include <hip/hip_runtime.h>
#include <math.h>

#define HID  512
#define SEQL 256
#define BATCH 2048
#define NCLS 10
#define NB   8      // batch columns per workgroup

// Transpose the 4 recurrent weight matrices [H][H] (row j, col k) into
// wt[g][k][j] so the main loop's per-k weight loads are lane-coalesced.
__global__ void transpose_w(const float* __restrict__ w0, const float* __restrict__ w1,
                            const float* __restrict__ w2, const float* __restrict__ w3,
                            float* __restrict__ wt)
{
    __shared__ float tile[32][33];
    const int g = blockIdx.z;
    const float* w = (g == 0) ? w0 : (g == 1) ? w1 : (g == 2) ? w2 : w3;
    const int jb = blockIdx.x * 32;
    const int kb = blockIdx.y * 32;
    const int tx = threadIdx.x, ty = threadIdx.y;   // 32 x 8
    #pragma unroll
    for (int r = 0; r < 32; r += 8)
        tile[ty + r][tx] = w[(jb + ty + r) * HID + (kb + tx)];
    __syncthreads();
    float* o = wt + g * HID * HID;
    #pragma unroll
    for (int r = 0; r < 32; r += 8)
        o[(kb + ty + r) * HID + (jb + tx)] = tile[tx][ty + r];
}

// Persistent LSTM: each workgroup owns NB=8 batch columns for all 256 steps.
// Thread j owns hidden row j: 4 gate accumulators x 8 columns in registers,
// cell state c in registers, h broadcast through LDS each step.
__global__ __launch_bounds__(512, 2) void lstm_persist(
    const float* __restrict__ x,                                   // [B][SEQ]
    const float* __restrict__ wgx, const float* __restrict__ wix,
    const float* __restrict__ wfx, const float* __restrict__ wox,  // [H]
    const float* __restrict__ bg,  const float* __restrict__ bi,
    const float* __restrict__ bf_, const float* __restrict__ bo,   // [H]
    const float* __restrict__ wt,                                  // [4][H][H] transposed
    const float* __restrict__ wph, const float* __restrict__ bp,   // [C][H], [C]
    const float* __restrict__ h_init, const float* __restrict__ c_init, // [H]
    float* __restrict__ out)                                       // [B][C]
{
    __shared__ float4 h_s4[HID * 2];    // h[k][0..7] as 2x float4 per k
    __shared__ float  x_s[NB * SEQL];
    float* h_s = reinterpret_cast<float*>(h_s4);

    const int j  = threadIdx.x;          // 0..511 = hidden row
    const int b0 = blockIdx.x * NB;      // first batch column of this WG

    // Preload this WG's x slice (coalesced along t).
    for (int i = j; i < NB * SEQL; i += 512)
        x_s[i] = x[(b0 + i / SEQL) * SEQL + (i % SEQL)];

    const float wxg = wgx[j], wxi = wix[j], wxf = wfx[j], wxo = wox[j];
    const float bgj = bg[j],  bij = bi[j],  bfj = bf_[j], boj = bo[j];

    float c_reg[NB];
    {
        const float c0 = c_init[j];
        const float h0 = h_init[j];
        #pragma unroll
        for (int c = 0; c < NB; c++) c_reg[c] = c0;
        h_s4[j * 2 + 0] = make_float4(h0, h0, h0, h0);
        h_s4[j * 2 + 1] = make_float4(h0, h0, h0, h0);
    }
    __syncthreads();

    const float* __restrict__ wtg = wt;
    const float* __restrict__ wti = wt + HID * HID;
    const float* __restrict__ wtf = wt + 2 * HID * HID;
    const float* __restrict__ wto = wt + 3 * HID * HID;

    for (int t = 0; t < SEQL; t++) {
        float ag[NB], ai[NB], af[NB], ao[NB];
        #pragma unroll
        for (int c = 0; c < NB; c++) {
            const float xv = x_s[c * SEQL + t];
            ag[c] = fmaf(wxg, xv, bgj);
            ai[c] = fmaf(wxi, xv, bij);
            af[c] = fmaf(wxf, xv, bfj);
            ao[c] = fmaf(wxo, xv, boj);
        }
        // K-loop: coalesced weight streams (lane j contiguous), h via LDS broadcast.
        #pragma unroll 4
        for (int k = 0; k < HID; k++) {
            const float wg = wtg[k * HID + j];
            const float wi = wti[k * HID + j];
            const float wf = wtf[k * HID + j];
            const float wo = wto[k * HID + j];
            const float4 ha = h_s4[k * 2 + 0];
            const float4 hb = h_s4[k * 2 + 1];
            const float hv[NB] = {ha.x, ha.y, ha.z, ha.w, hb.x, hb.y, hb.z, hb.w};
            #pragma unroll
            for (int c = 0; c < NB; c++) {
                ag[c] = fmaf(wg, hv[c], ag[c]);
                ai[c] = fmaf(wi, hv[c], ai[c]);
                af[c] = fmaf(wf, hv[c], af[c]);
                ao[c] = fmaf(wo, hv[c], ao[c]);
            }
        }
        __syncthreads();   // all lanes done reading h_s for step t
        float hnew[NB];
        #pragma unroll
        for (int c = 0; c < NB; c++) {
            const float g  = tanhf(ag[c]);
            const float ii = 1.f / (1.f + expf(-ai[c]));
            const float ff = 1.f / (1.f + expf(-af[c]));
            const float oo = 1.f / (1.f + expf(-ao[c]));
            const float cc = fmaf(g, ii, c_reg[c] * ff);
            c_reg[c] = cc;
            hnew[c]  = tanhf(cc) * oo;
        }
        h_s4[j * 2 + 0] = make_float4(hnew[0], hnew[1], hnew[2], hnew[3]);
        h_s4[j * 2 + 1] = make_float4(hnew[4], hnew[5], hnew[6], hnew[7]);
        __syncthreads();   // h_s ready for step t+1
    }

    // Epilogue: out[b][cls] = bp[cls] + sum_k wph[cls][k] * h[k][b]
    if (j < NB * NCLS) {
        const int col = j / NCLS, cls = j % NCLS;
        float s = bp[cls];
        for (int k = 0; k < HID; k++)
            s = fmaf(wph[cls * HID + k], h_s[k * NB + col], s);
        out[(b0 + col) * NCLS + cls] = s;
    }
}

extern "C" void kernel_launch(void* const* d_in, const int* in_sizes, int n_in,
                              void* d_out, int out_size, void* d_ws, size_t ws_size,
                              hipStream_t stream)
{
    const float* x   = (const float*)d_in[0];
    const float* wgx = (const float*)d_in[1];
    const float* wix = (const float*)d_in[2];
    const float* wfx = (const float*)d_in[3];
    const float* wox = (const float*)d_in[4];
    const float* wgh = (const float*)d_in[5];
    const float* wih = (const float*)d_in[6];
    const float* wfh = (const float*)d_in[7];
    const float* woh = (const float*)d_in[8];
    const float* bg  = (const float*)d_in[9];
    const float* bi  = (const float*)d_in[10];
    const float* bf  = (const float*)d_in[11];
    const float* bo  = (const float*)d_in[12];
    const float* wph = (const float*)d_in[13];
    const float* bp  = (const float*)d_in[14];
    const float* h0  = (const float*)d_in[15];
    const float* c0  = (const float*)d_in[16];
    float* out = (float*)d_out;
    float* wt  = (float*)d_ws;   // 4*512*512*4 B = 4 MiB scratch

    transpose_w<<<dim3(16, 16, 4), dim3(32, 8), 0, stream>>>(wgh, wih, wfh, woh, wt);
    lstm_persist<<<dim3(BATCH / NB), dim3(512), 0, stream>>>(
        x, wgx, wix, wfx, wox, bg, bi, bf, bo, wt, wph, bp, h0, c0, out);
}